// Round 7
// baseline (412.907 us; speedup 1.0000x reference)
//
#include <hip/hip_runtime.h>

#define N_NODES 50000
#define MPAD 50176            // 392*128, node-buffer row padding for GEMM staging
#define N_EDGES 800000
#define DIM 256
#define N_GRAPHS 500
#define N_OUT 10
#define BN_EPS 1e-5f
#define SCAN_BS 1024
#define KSPLIT 4

typedef unsigned int u32;
typedef short bf16x8 __attribute__((ext_vector_type(8)));
typedef unsigned short us8 __attribute__((ext_vector_type(8)));
typedef float f32x4 __attribute__((ext_vector_type(4)));

typedef __attribute__((address_space(1))) const unsigned int gas_u32;
typedef __attribute__((address_space(3))) unsigned int las_u32;

__device__ inline void g2l16(const void* g, void* l) {
    // async global->LDS, 16 bytes per lane; LDS dest = wave-uniform base + lane*16
    __builtin_amdgcn_global_load_lds((gas_u32*)g, (las_u32*)l, 16, 0, 0);
}

__device__ inline float b2f(unsigned short u) {
    union { u32 i; float f; } c; c.i = ((u32)u) << 16; return c.f;
}
__device__ inline unsigned short f2b(float f) {   // round-to-nearest-even
    u32 x = __builtin_bit_cast(u32, f);
    return (unsigned short)((x + 0x7FFFu + ((x >> 16) & 1u)) >> 16);
}

// ---------------- CSR build ----------------
__global__ void zero_i(int* __restrict__ p, int n) {
    int i = blockIdx.x * blockDim.x + threadIdx.x;
    if (i < n) p[i] = 0;
}
__global__ void hist_dst(const int* __restrict__ dst, int* __restrict__ deg) {
    int e = blockIdx.x * blockDim.x + threadIdx.x;
    if (e < N_EDGES) atomicAdd(&deg[dst[e]], 1);
}
__global__ void scan_phase1(const int* __restrict__ deg, int* __restrict__ rowptr,
                            int* __restrict__ bsum, int n) {
    __shared__ int sh[SCAN_BS];
    int i = blockIdx.x * SCAN_BS + threadIdx.x;
    int v = (i < n) ? deg[i] : 0;
    sh[threadIdx.x] = v;
    __syncthreads();
    for (int off = 1; off < SCAN_BS; off <<= 1) {
        int t = (threadIdx.x >= off) ? sh[threadIdx.x - off] : 0;
        __syncthreads();
        sh[threadIdx.x] += t;
        __syncthreads();
    }
    if (i < n) rowptr[i] = sh[threadIdx.x] - v;
    if (threadIdx.x == SCAN_BS - 1) bsum[blockIdx.x] = sh[threadIdx.x];
}
__global__ void scan_phase2(int* __restrict__ bsum, int nb) {
    if (threadIdx.x == 0 && blockIdx.x == 0) {
        int run = 0;
        for (int b = 0; b < nb; b++) { int v = bsum[b]; bsum[b] = run; run += v; }
    }
}
__global__ void scan_phase3(int* __restrict__ rowptr, int* __restrict__ cursor,
                            const int* __restrict__ bsum, int n) {
    int i = blockIdx.x * SCAN_BS + threadIdx.x;
    if (i < n) {
        int v = rowptr[i] + bsum[blockIdx.x];
        rowptr[i] = v;
        cursor[i] = v;
    }
    if (i == 0) rowptr[n] = N_EDGES;
}
__global__ void fill_csr(const int* __restrict__ src, const int* __restrict__ dst,
                         int* __restrict__ cursor, int* __restrict__ col) {
    int e = blockIdx.x * blockDim.x + threadIdx.x;
    if (e < N_EDGES) {
        int p = atomicAdd(&cursor[dst[e]], 1);
        col[p] = src[e];
    }
}
__global__ void graph_starts(const int* __restrict__ batch, int* __restrict__ gstart) {
    int g = blockIdx.x * blockDim.x + threadIdx.x;
    if (g > N_GRAPHS) return;
    if (g == N_GRAPHS) { gstart[g] = N_NODES; return; }
    int lo = 0, hi = N_NODES;
    while (lo < hi) { int mid = (lo + hi) >> 1; if (batch[mid] < g) lo = mid + 1; else hi = mid; }
    gstart[g] = lo;
}

// ---------------- conversions ----------------
__global__ void conv_x(const float4* __restrict__ in, ushort4* __restrict__ out, int n4) {
    int i = blockIdx.x * blockDim.x + threadIdx.x;
    if (i < n4) {
        float4 v = in[i];
        ushort4 o; o.x = f2b(v.x); o.y = f2b(v.y); o.z = f2b(v.z); o.w = f2b(v.w);
        out[i] = o;
    }
}
// Wt[mat][n][k] = bf16(W[mat][k][n])
__global__ void conv_wt4(const float* __restrict__ W0, const float* __restrict__ W1,
                         const float* __restrict__ W2, const float* __restrict__ W3,
                         unsigned short* __restrict__ Wt) {
    int mat = blockIdx.y;
    const float* W = (mat == 0) ? W0 : (mat == 1) ? W1 : (mat == 2) ? W2 : W3;
    int n = blockIdx.x;
    int k = threadIdx.x;
    Wt[((size_t)mat << 16) + (size_t)n * 256 + k] = f2b(W[(size_t)k * 256 + n]);
}
__global__ void make_ss(const float* __restrict__ bias, const float* __restrict__ gamma,
                        const float* __restrict__ beta, const float* __restrict__ mean,
                        const float* __restrict__ var, float* __restrict__ scale,
                        float* __restrict__ shift, int has_bn) {
    int i = threadIdx.x;
    if (has_bn) {
        float s = gamma[i] * rsqrtf(var[i] + BN_EPS);
        scale[i] = s;
        shift[i] = (bias[i] - mean[i]) * s + beta[i];
    } else {
        scale[i] = 1.f;
        shift[i] = bias[i];
    }
}

// ---------------- gather aggregate (bf16): out[i] = feat[i] + sum_{j in N(i)} feat[j] ----------------
// one wave per node; two 32-lane halves own alternate edges; 16 B/lane loads; x8 unroll (16 streams/wave).
__global__ void gather_bf(const unsigned short* __restrict__ feat,
                          const int* __restrict__ col,
                          const int* __restrict__ rowptr,
                          unsigned short* __restrict__ out) {
    int node = blockIdx.x * 4 + (threadIdx.x >> 6);
    if (node >= N_NODES) return;
    int lane = threadIdx.x & 63;
    int half = lane >> 5;
    int d8 = (lane & 31) * 8;          // 8 bf16 = 16 B per lane
    float acc[8];
    #pragma unroll
    for (int j = 0; j < 8; j++) acc[j] = 0.f;
    if (half == 0) {
        us8 own = *reinterpret_cast<const us8*>(&feat[(size_t)node * DIM + d8]);
        #pragma unroll
        for (int j = 0; j < 8; j++) acc[j] = b2f((unsigned short)own[j]);
    }
    int s = rowptr[node], e = rowptr[node + 1];
    int i = s + half;
    for (; i + 14 < e; i += 16) {      // 8 edges per half per iter, 16 row-streams/wave
        int nn[8];
        #pragma unroll
        for (int q = 0; q < 8; q++) nn[q] = col[i + 2 * q];
        us8 v[8];
        #pragma unroll
        for (int q = 0; q < 8; q++)
            v[q] = *reinterpret_cast<const us8*>(&feat[(size_t)nn[q] * DIM + d8]);
        #pragma unroll
        for (int q = 0; q < 8; q++)
            #pragma unroll
            for (int j = 0; j < 8; j++)
                acc[j] += b2f((unsigned short)v[q][j]);
    }
    for (; i < e; i += 2) {
        int n0 = col[i];
        us8 v0 = *reinterpret_cast<const us8*>(&feat[(size_t)n0 * DIM + d8]);
        #pragma unroll
        for (int j = 0; j < 8; j++) acc[j] += b2f((unsigned short)v0[j]);
    }
    #pragma unroll
    for (int j = 0; j < 8; j++) acc[j] += __shfl_xor(acc[j], 32, 64);
    if (half == 0) {
        us8 o;
        #pragma unroll
        for (int j = 0; j < 8; j++) o[j] = (short)f2b(acc[j]);
        *reinterpret_cast<us8*>(&out[(size_t)node * DIM + d8]) = o;
    }
}

// ---------------- bf16 MFMA GEMM:  C[M x 256] = relu((A @ W)*scale + shift) ----------------
// 512 threads, block tile 128x256 (full N), 8 waves as 2M x 4N, wave 64x64, BK=32.
// Double-buffered staging: issue next K-tile's global_load_lds before computing current.
__global__ __launch_bounds__(512)
void gemm_bf16(const unsigned short* __restrict__ A,
               const unsigned short* __restrict__ Wt,
               const float* __restrict__ scale,
               const float* __restrict__ shift,
               unsigned short* __restrict__ C, int M) {
    __shared__ unsigned short Asb[2][128 * 32];   // 2 x 8 KB
    __shared__ unsigned short Bsb[2][256 * 32];   // 2 x 16 KB
    int t = threadIdx.x;
    int wave = t >> 6, lane = t & 63;
    int m0 = blockIdx.x * 128;
    int wr = (wave >> 2) * 64;
    int wc = (wave & 3) * 64;

    // per-thread staging source addresses (k0 added per step)
    int cb = (t & 3) * 16;                       // byte offset within 64B k-row
    const char* Ab  = (const char*)A  + (size_t)(m0 + (t >> 2)) * 512 + cb;
    const char* Bb0 = (const char*)Wt + (size_t)(t >> 2) * 512 + cb;          // rows 0..127
    const char* Bb1 = (const char*)Wt + (size_t)(128 + (t >> 2)) * 512 + cb;  // rows 128..255

    f32x4 acc[4][4];
    #pragma unroll
    for (int m = 0; m < 4; m++)
        #pragma unroll
        for (int n = 0; n < 4; n++)
            acc[m][n] = (f32x4){0.f, 0.f, 0.f, 0.f};

    int rsel = lane & 15;
    int ksel = (lane >> 4) * 8;

    // prologue: stage K-tile 0 into buffer 0
    g2l16(Ab,  (char*)Asb[0] + (size_t)t * 16);
    g2l16(Bb0, (char*)Bsb[0] + (size_t)t * 16);
    g2l16(Bb1, (char*)Bsb[0] + (size_t)(512 + t) * 16);
    __syncthreads();

    int cur = 0;
    for (int ks = 0; ks < 8; ks++) {
        if (ks < 7) {   // stage next K-tile into the other buffer (flies during compute)
            size_t ko = (size_t)(ks + 1) * 64;   // 32 bf16 = 64 bytes
            g2l16(Ab + ko,  (char*)Asb[cur ^ 1] + (size_t)t * 16);
            g2l16(Bb0 + ko, (char*)Bsb[cur ^ 1] + (size_t)t * 16);
            g2l16(Bb1 + ko, (char*)Bsb[cur ^ 1] + (size_t)(512 + t) * 16);
        }
        const unsigned short* As = Asb[cur];
        const unsigned short* Bs = Bsb[cur];
        bf16x8 af[4], bfr[4];
        #pragma unroll
        for (int m = 0; m < 4; m++)
            af[m] = *(const bf16x8*)&As[(size_t)(wr + m * 16 + rsel) * 32 + ksel];
        #pragma unroll
        for (int n = 0; n < 4; n++)
            bfr[n] = *(const bf16x8*)&Bs[(size_t)(wc + n * 16 + rsel) * 32 + ksel];
        #pragma unroll
        for (int m = 0; m < 4; m++)
            #pragma unroll
            for (int n = 0; n < 4; n++)
                acc[m][n] = __builtin_amdgcn_mfma_f32_16x16x32_bf16(af[m], bfr[n], acc[m][n], 0, 0, 0);
        __syncthreads();   // drains vmcnt (next tile ready) + lgkm, gates buffer reuse
        cur ^= 1;
    }

    // epilogue: C/D frag mapping col=lane&15, row=(lane>>4)*4+reg
    int cr = lane >> 4;
    #pragma unroll
    for (int n = 0; n < 4; n++) {
        int colg = wc + n * 16 + rsel;
        float s = scale[colg], sh = shift[colg];
        #pragma unroll
        for (int m = 0; m < 4; m++) {
            int rowb = m0 + wr + m * 16 + cr * 4;
            #pragma unroll
            for (int r = 0; r < 4; r++) {
                int row = rowb + r;
                if (row < M) {
                    float v = fmaxf(acc[m][n][r] * s + sh, 0.f);
                    C[(size_t)row * 256 + colg] = f2b(v);
                }
            }
        }
    }
}

// ---------------- pooling (bf16 in, f32 out, concatenated [g][512]) ----------------
__global__ void pool_seg(const unsigned short* __restrict__ h1,
                         const unsigned short* __restrict__ h2,
                         const int* __restrict__ gstart,
                         float* __restrict__ pcat) {
    int g = blockIdx.x;
    int t = threadIdx.x;
    int s = gstart[g], e = gstart[g + 1];
    float a1 = 0.f, a2 = 0.f;
    for (int n = s; n < e; n++) {
        a1 += b2f(h1[(size_t)n * DIM + t]);
        a2 += b2f(h2[(size_t)n * DIM + t]);
    }
    pcat[(size_t)g * 512 + t]       = a1;
    pcat[(size_t)g * 512 + 256 + t] = a2;
}

// ---------------- head stage 1 (split-K): Hpart[z][500][768] = pcat[:, z*128:(z+1)*128] @ W1-slice ----
// 64x64 tile, 256 threads (16x16, 4x4 micro), grid (12, 8, 4)
__global__ void head1(const float* __restrict__ A,    // [500][512]
                      const float* __restrict__ W1,   // [512][768]
                      float* __restrict__ Hpart) {    // [KSPLIT][500][768]
    __shared__ float As[16][65];
    __shared__ float Bs[16][65];
    int t = threadIdx.x;
    int m0 = blockIdx.y * 64;
    int n0 = blockIdx.x * 64;
    int kz = blockIdx.z * (512 / KSPLIT);
    int tx = t & 15, ty = t >> 4;
    float acc[4][4] = {};
    for (int k0 = kz; k0 < kz + 512 / KSPLIT; k0 += 16) {
        #pragma unroll
        for (int i = 0; i < 4; i++) {
            int r = (t >> 4) + i * 16;
            int k = t & 15;
            int gr = m0 + r;
            As[k][r] = (gr < N_GRAPHS) ? A[(size_t)gr * 512 + k0 + k] : 0.f;
        }
        #pragma unroll
        for (int i = 0; i < 4; i++) {
            int k = (t >> 6) + i * 4;
            int n = t & 63;
            Bs[k][n] = W1[(size_t)(k0 + k) * 768 + n0 + n];
        }
        __syncthreads();
        #pragma unroll
        for (int k = 0; k < 16; k++) {
            float a[4], b[4];
            #pragma unroll
            for (int i = 0; i < 4; i++) a[i] = As[k][ty * 4 + i];
            #pragma unroll
            for (int j = 0; j < 4; j++) b[j] = Bs[k][tx * 4 + j];
            #pragma unroll
            for (int i = 0; i < 4; i++)
                #pragma unroll
                for (int j = 0; j < 4; j++)
                    acc[i][j] += a[i] * b[j];
        }
        __syncthreads();
    }
    float* Hz = Hpart + (size_t)blockIdx.z * N_GRAPHS * 768;
    #pragma unroll
    for (int i = 0; i < 4; i++) {
        int gm = m0 + ty * 4 + i;
        if (gm >= N_GRAPHS) continue;
        #pragma unroll
        for (int j = 0; j < 4; j++) {
            int gn = n0 + tx * 4 + j;
            Hz[(size_t)gm * 768 + gn] = acc[i][j];
        }
    }
}

// ---------------- head stage 2: sum partials + bias + relu, GEMV, log_softmax ----------------
__global__ void head2(const float* __restrict__ Hpart, const float* __restrict__ b1,
                      const float* __restrict__ W2, const float* __restrict__ b2,
                      float* __restrict__ out) {
    int g = blockIdx.x;
    int lane = threadIdx.x;   // 64
    float part[N_OUT];
    #pragma unroll
    for (int o = 0; o < N_OUT; o++) part[o] = 0.f;
    for (int k = lane; k < 768; k += 64) {
        float hv = b1[k];
        #pragma unroll
        for (int z = 0; z < KSPLIT; z++)
            hv += Hpart[((size_t)z * N_GRAPHS + g) * 768 + k];
        hv = fmaxf(hv, 0.f);
        #pragma unroll
        for (int o = 0; o < N_OUT; o++) part[o] += hv * W2[(size_t)k * N_OUT + o];
    }
    #pragma unroll
    for (int o = 0; o < N_OUT; o++) {
        #pragma unroll
        for (int off = 32; off > 0; off >>= 1)
            part[o] += __shfl_down(part[o], off, 64);
    }
    if (lane == 0) {
        float logits[N_OUT];
        float mx = -1e30f;
        #pragma unroll
        for (int o = 0; o < N_OUT; o++) { logits[o] = part[o] + b2[o]; mx = fmaxf(mx, logits[o]); }
        float ssum = 0.f;
        #pragma unroll
        for (int o = 0; o < N_OUT; o++) ssum += expf(logits[o] - mx);
        float lse = logf(ssum);
        #pragma unroll
        for (int o = 0; o < N_OUT; o++)
            out[(size_t)g * N_OUT + o] = logits[o] - mx - lse;
    }
}

extern "C" void kernel_launch(void* const* d_in, const int* in_sizes, int n_in,
                              void* d_out, int out_size, void* d_ws, size_t ws_size,
                              hipStream_t stream) {
    const float* x     = (const float*)d_in[0];
    const int*   ei    = (const int*)d_in[1];
    const int*   batch = (const int*)d_in[2];
    const float* W1a = (const float*)d_in[3];
    const float* b1a = (const float*)d_in[4];
    const float* g1a = (const float*)d_in[5];
    const float* be1a= (const float*)d_in[6];
    const float* m1a = (const float*)d_in[7];
    const float* v1a = (const float*)d_in[8];
    const float* W2a = (const float*)d_in[9];
    const float* b2a = (const float*)d_in[10];
    const float* W1b = (const float*)d_in[11];
    const float* b1b = (const float*)d_in[12];
    const float* g1b = (const float*)d_in[13];
    const float* be1b= (const float*)d_in[14];
    const float* m1b = (const float*)d_in[15];
    const float* v1b = (const float*)d_in[16];
    const float* W2b = (const float*)d_in[17];
    const float* b2b = (const float*)d_in[18];
    const float* lin1_W = (const float*)d_in[19];
    const float* lin1_b = (const float*)d_in[20];
    const float* lin2_W = (const float*)d_in[21];
    const float* lin2_b = (const float*)d_in[22];

    const size_t NBUF = (size_t)MPAD * DIM;
    char* ws = (char*)d_ws;
    unsigned short* agg  = (unsigned short*)ws;            ws += NBUF * 2;
    unsigned short* mid  = (unsigned short*)ws;            ws += NBUF * 2;
    unsigned short* h1   = (unsigned short*)ws;            ws += NBUF * 2;
    unsigned short* h2   = (unsigned short*)ws;            ws += NBUF * 2;
    unsigned short* x_bf = (unsigned short*)ws;            ws += (size_t)N_NODES * DIM * 2;
    unsigned short* Wt   = (unsigned short*)ws;            ws += 4 * 65536 * 2;
    float* ss    = (float*)ws;                             ws += 8 * 256 * 4;
    float* pcat  = (float*)ws;                             ws += (size_t)N_GRAPHS * 512 * 4;
    float* Hpart = (float*)ws;                             ws += (size_t)KSPLIT * N_GRAPHS * 768 * 4;
    int* deg     = (int*)ws;                               ws += (size_t)N_NODES * 4;
    int* cursor  = (int*)ws;                               ws += (size_t)N_NODES * 4;
    int* rowptr  = (int*)ws;                               ws += (size_t)(N_NODES + 1) * 4;
    int* bsum    = (int*)ws;                               ws += 64 * 4;
    int* col     = (int*)ws;                               ws += (size_t)N_EDGES * 4;
    int* gstart  = (int*)ws;

    const int* srcE = ei;
    const int* dstE = ei + N_EDGES;

    const int nscan = (N_NODES + SCAN_BS - 1) / SCAN_BS;

    // ---- CSR build (by dst), shared by both layers ----
    zero_i<<<(N_NODES + 255) / 256, 256, 0, stream>>>(deg, N_NODES);
    hist_dst<<<(N_EDGES + 255) / 256, 256, 0, stream>>>(dstE, deg);
    scan_phase1<<<nscan, SCAN_BS, 0, stream>>>(deg, rowptr, bsum, N_NODES);
    scan_phase2<<<1, 64, 0, stream>>>(bsum, nscan);
    scan_phase3<<<nscan, SCAN_BS, 0, stream>>>(rowptr, cursor, bsum, N_NODES);
    fill_csr<<<(N_EDGES + 255) / 256, 256, 0, stream>>>(srcE, dstE, cursor, col);
    graph_starts<<<2, 256, 0, stream>>>(batch, gstart);

    // ---- precompute ----
    conv_x<<<(N_NODES * DIM / 4 + 255) / 256, 256, 0, stream>>>(
        (const float4*)x, (ushort4*)x_bf, N_NODES * DIM / 4);
    dim3 wt_grid(256, 4);
    conv_wt4<<<wt_grid, 256, 0, stream>>>(W1a, W2a, W1b, W2b, Wt);
    make_ss<<<1, 256, 0, stream>>>(b1a, g1a, be1a, m1a, v1a, ss + 0 * 512, ss + 0 * 512 + 256, 1);
    make_ss<<<1, 256, 0, stream>>>(b2a, nullptr, nullptr, nullptr, nullptr, ss + 1 * 512, ss + 1 * 512 + 256, 0);
    make_ss<<<1, 256, 0, stream>>>(b1b, g1b, be1b, m1b, v1b, ss + 2 * 512, ss + 2 * 512 + 256, 1);
    make_ss<<<1, 256, 0, stream>>>(b2b, nullptr, nullptr, nullptr, nullptr, ss + 3 * 512, ss + 3 * 512 + 256, 0);

    // ---- layer 1 ----
    gather_bf<<<(N_NODES + 3) / 4, 256, 0, stream>>>(x_bf, col, rowptr, agg);
    gemm_bf16<<<MPAD / 128, 512, 0, stream>>>(agg, Wt + 0 * 65536, ss + 0 * 512, ss + 0 * 512 + 256, mid, N_NODES);
    gemm_bf16<<<MPAD / 128, 512, 0, stream>>>(mid, Wt + 1 * 65536, ss + 1 * 512, ss + 1 * 512 + 256, h1, N_NODES);

    // ---- layer 2 ----
    gather_bf<<<(N_NODES + 3) / 4, 256, 0, stream>>>(h1, col, rowptr, agg);
    gemm_bf16<<<MPAD / 128, 512, 0, stream>>>(agg, Wt + 2 * 65536, ss + 2 * 512, ss + 2 * 512 + 256, mid, N_NODES);
    gemm_bf16<<<MPAD / 128, 512, 0, stream>>>(mid, Wt + 3 * 65536, ss + 3 * 512, ss + 3 * 512 + 256, h2, N_NODES);

    // ---- pooling + head ----
    pool_seg<<<N_GRAPHS, 256, 0, stream>>>(h1, h2, gstart, pcat);
    dim3 h1grid(12, 8, KSPLIT);
    head1<<<h1grid, 256, 0, stream>>>(pcat, lin1_W, Hpart);
    head2<<<N_GRAPHS, 64, 0, stream>>>(Hpart, lin1_b, lin2_W, lin2_b, (float*)d_out);
}

// Round 8
// 395.285 us; speedup vs baseline: 1.0446x; 1.0446x over previous
//
#include <hip/hip_runtime.h>

#define N_NODES 50000
#define MPAD 50176            // 392*128, node-buffer row padding for GEMM staging
#define N_EDGES 800000
#define DIM 256
#define N_GRAPHS 500
#define N_OUT 10
#define BN_EPS 1e-5f
#define SCAN_BS 1024
#define KSPLIT 4

typedef unsigned int u32;
typedef short bf16x8 __attribute__((ext_vector_type(8)));
typedef unsigned short us8 __attribute__((ext_vector_type(8)));
typedef float f32x4 __attribute__((ext_vector_type(4)));

typedef __attribute__((address_space(1))) const unsigned int gas_u32;
typedef __attribute__((address_space(3))) unsigned int las_u32;

__device__ inline void g2l16(const void* g, void* l) {
    // async global->LDS, 16 bytes per lane; LDS dest = wave-uniform base + lane*16
    __builtin_amdgcn_global_load_lds((gas_u32*)g, (las_u32*)l, 16, 0, 0);
}

__device__ inline float b2f(unsigned short u) {
    union { u32 i; float f; } c; c.i = ((u32)u) << 16; return c.f;
}
__device__ inline unsigned short f2b(float f) {   // round-to-nearest-even
    u32 x = __builtin_bit_cast(u32, f);
    return (unsigned short)((x + 0x7FFFu + ((x >> 16) & 1u)) >> 16);
}

// ---------------- CSR build ----------------
__global__ void zero_i(int* __restrict__ p, int n) {
    int i = blockIdx.x * blockDim.x + threadIdx.x;
    if (i < n) p[i] = 0;
}
__global__ void hist_dst(const int* __restrict__ dst, int* __restrict__ deg) {
    int e = blockIdx.x * blockDim.x + threadIdx.x;
    if (e < N_EDGES) atomicAdd(&deg[dst[e]], 1);
}
__global__ void scan_phase1(const int* __restrict__ deg, int* __restrict__ rowptr,
                            int* __restrict__ bsum, int n) {
    __shared__ int sh[SCAN_BS];
    int i = blockIdx.x * SCAN_BS + threadIdx.x;
    int v = (i < n) ? deg[i] : 0;
    sh[threadIdx.x] = v;
    __syncthreads();
    for (int off = 1; off < SCAN_BS; off <<= 1) {
        int t = (threadIdx.x >= off) ? sh[threadIdx.x - off] : 0;
        __syncthreads();
        sh[threadIdx.x] += t;
        __syncthreads();
    }
    if (i < n) rowptr[i] = sh[threadIdx.x] - v;
    if (threadIdx.x == SCAN_BS - 1) bsum[blockIdx.x] = sh[threadIdx.x];
}
__global__ void scan_phase2(int* __restrict__ bsum, int nb) {
    if (threadIdx.x == 0 && blockIdx.x == 0) {
        int run = 0;
        for (int b = 0; b < nb; b++) { int v = bsum[b]; bsum[b] = run; run += v; }
    }
}
__global__ void scan_phase3(int* __restrict__ rowptr, int* __restrict__ cursor,
                            const int* __restrict__ bsum, int n) {
    int i = blockIdx.x * SCAN_BS + threadIdx.x;
    if (i < n) {
        int v = rowptr[i] + bsum[blockIdx.x];
        rowptr[i] = v;
        cursor[i] = v;
    }
    if (i == 0) rowptr[n] = N_EDGES;
}
__global__ void fill_csr(const int* __restrict__ src, const int* __restrict__ dst,
                         int* __restrict__ cursor, int* __restrict__ col) {
    int e = blockIdx.x * blockDim.x + threadIdx.x;
    if (e < N_EDGES) {
        int p = atomicAdd(&cursor[dst[e]], 1);
        col[p] = src[e];
    }
}
__global__ void graph_starts(const int* __restrict__ batch, int* __restrict__ gstart) {
    int g = blockIdx.x * blockDim.x + threadIdx.x;
    if (g > N_GRAPHS) return;
    if (g == N_GRAPHS) { gstart[g] = N_NODES; return; }
    int lo = 0, hi = N_NODES;
    while (lo < hi) { int mid = (lo + hi) >> 1; if (batch[mid] < g) lo = mid + 1; else hi = mid; }
    gstart[g] = lo;
}

// ---------------- conversions ----------------
__global__ void conv_x(const float4* __restrict__ in, ushort4* __restrict__ out, int n4) {
    int i = blockIdx.x * blockDim.x + threadIdx.x;
    if (i < n4) {
        float4 v = in[i];
        ushort4 o; o.x = f2b(v.x); o.y = f2b(v.y); o.z = f2b(v.z); o.w = f2b(v.w);
        out[i] = o;
    }
}
// Wt[mat][n][k] = bf16(W[mat][k][n])
__global__ void conv_wt4(const float* __restrict__ W0, const float* __restrict__ W1,
                         const float* __restrict__ W2, const float* __restrict__ W3,
                         unsigned short* __restrict__ Wt) {
    int mat = blockIdx.y;
    const float* W = (mat == 0) ? W0 : (mat == 1) ? W1 : (mat == 2) ? W2 : W3;
    int n = blockIdx.x;
    int k = threadIdx.x;
    Wt[((size_t)mat << 16) + (size_t)n * 256 + k] = f2b(W[(size_t)k * 256 + n]);
}
__global__ void make_ss(const float* __restrict__ bias, const float* __restrict__ gamma,
                        const float* __restrict__ beta, const float* __restrict__ mean,
                        const float* __restrict__ var, float* __restrict__ scale,
                        float* __restrict__ shift, int has_bn) {
    int i = threadIdx.x;
    if (has_bn) {
        float s = gamma[i] * rsqrtf(var[i] + BN_EPS);
        scale[i] = s;
        shift[i] = (bias[i] - mean[i]) * s + beta[i];
    } else {
        scale[i] = 1.f;
        shift[i] = bias[i];
    }
}

// ---------------- gather aggregate (bf16): out[i] = feat[i] + sum_{j in N(i)} feat[j] ----------------
// one wave per node; two 32-lane halves own alternate edges; 16 B/lane loads; x4 unroll (8 streams/wave).
__global__ void gather_bf(const unsigned short* __restrict__ feat,
                          const int* __restrict__ col,
                          const int* __restrict__ rowptr,
                          unsigned short* __restrict__ out) {
    int node = blockIdx.x * 4 + (threadIdx.x >> 6);
    if (node >= N_NODES) return;
    int lane = threadIdx.x & 63;
    int half = lane >> 5;
    int d8 = (lane & 31) * 8;          // 8 bf16 = 16 B per lane
    float acc[8];
    #pragma unroll
    for (int j = 0; j < 8; j++) acc[j] = 0.f;
    if (half == 0) {
        us8 own = *reinterpret_cast<const us8*>(&feat[(size_t)node * DIM + d8]);
        #pragma unroll
        for (int j = 0; j < 8; j++) acc[j] = b2f((unsigned short)own[j]);
    }
    int s = rowptr[node], e = rowptr[node + 1];
    int i = s + half;
    for (; i + 6 < e; i += 8) {        // 4 edges per half per iter
        int n0 = col[i], n1 = col[i + 2], n2 = col[i + 4], n3 = col[i + 6];
        us8 v0 = *reinterpret_cast<const us8*>(&feat[(size_t)n0 * DIM + d8]);
        us8 v1 = *reinterpret_cast<const us8*>(&feat[(size_t)n1 * DIM + d8]);
        us8 v2 = *reinterpret_cast<const us8*>(&feat[(size_t)n2 * DIM + d8]);
        us8 v3 = *reinterpret_cast<const us8*>(&feat[(size_t)n3 * DIM + d8]);
        #pragma unroll
        for (int j = 0; j < 8; j++)
            acc[j] += (b2f((unsigned short)v0[j]) + b2f((unsigned short)v1[j]))
                    + (b2f((unsigned short)v2[j]) + b2f((unsigned short)v3[j]));
    }
    for (; i < e; i += 2) {
        int n0 = col[i];
        us8 v0 = *reinterpret_cast<const us8*>(&feat[(size_t)n0 * DIM + d8]);
        #pragma unroll
        for (int j = 0; j < 8; j++) acc[j] += b2f((unsigned short)v0[j]);
    }
    #pragma unroll
    for (int j = 0; j < 8; j++) acc[j] += __shfl_xor(acc[j], 32, 64);
    if (half == 0) {
        us8 o;
        #pragma unroll
        for (int j = 0; j < 8; j++) o[j] = (short)f2b(acc[j]);
        *reinterpret_cast<us8*>(&out[(size_t)node * DIM + d8]) = o;
    }
}

// ---------------- bf16 MFMA GEMM:  C[M x 256] = relu((A @ W)*scale + shift) ----------------
// 512 threads, block tile 128x256 (full N), 8 waves as 2M x 4N, wave 64x64, BK=32.
// 2-deep counted-vmcnt pipeline: raw s_barrier + s_waitcnt vmcnt(3); prefetch loads
// stay in flight across barriers (never drained to 0 until the last tile).
__global__ __launch_bounds__(512)
void gemm_bf16(const unsigned short* __restrict__ A,
               const unsigned short* __restrict__ Wt,
               const float* __restrict__ scale,
               const float* __restrict__ shift,
               unsigned short* __restrict__ C, int M) {
    __shared__ unsigned short Asb[2][128 * 32];   // 2 x 8 KB
    __shared__ unsigned short Bsb[2][256 * 32];   // 2 x 16 KB
    int t = threadIdx.x;
    int wave = t >> 6, lane = t & 63;
    int m0 = blockIdx.x * 128;
    int wr = (wave >> 2) * 64;
    int wc = (wave & 3) * 64;

    // per-thread staging source addresses (tile offset added per step)
    int cb = (t & 3) * 16;                       // byte offset within 64B k-row
    const char* Ab  = (const char*)A  + (size_t)(m0 + (t >> 2)) * 512 + cb;
    const char* Bb0 = (const char*)Wt + (size_t)(t >> 2) * 512 + cb;          // rows 0..127
    const char* Bb1 = (const char*)Wt + (size_t)(128 + (t >> 2)) * 512 + cb;  // rows 128..255

    f32x4 acc[4][4];
    #pragma unroll
    for (int m = 0; m < 4; m++)
        #pragma unroll
        for (int n = 0; n < 4; n++)
            acc[m][n] = (f32x4){0.f, 0.f, 0.f, 0.f};

    int rsel = lane & 15;
    int ksel = (lane >> 4) * 8;

    // prologue: stage tiles 0 and 1 (3 loads each per thread -> 6 outstanding)
    #pragma unroll
    for (int p = 0; p < 2; p++) {
        size_t ko = (size_t)p * 64;   // 32 bf16 = 64 bytes per K-tile
        g2l16(Ab + ko,  (char*)Asb[p] + (size_t)t * 16);
        g2l16(Bb0 + ko, (char*)Bsb[p] + (size_t)t * 16);
        g2l16(Bb1 + ko, (char*)Bsb[p] + (size_t)(512 + t) * 16);
    }

    #pragma unroll
    for (int ks = 0; ks < 8; ks++) {
        const int cur = ks & 1;
        // wait for buf[cur]'s 3 loads (next buf's 3 remain in flight), then sync
        if (ks < 7) asm volatile("s_waitcnt vmcnt(3)" ::: "memory");
        else        asm volatile("s_waitcnt vmcnt(0)" ::: "memory");
        __builtin_amdgcn_s_barrier();
        asm volatile("" ::: "memory");   // keep LDS reads below the barrier

        const unsigned short* As = Asb[cur];
        const unsigned short* Bs = Bsb[cur];
        bf16x8 af[4], bfr[4];
        #pragma unroll
        for (int m = 0; m < 4; m++)
            af[m] = *(const bf16x8*)&As[(size_t)(wr + m * 16 + rsel) * 32 + ksel];
        #pragma unroll
        for (int n = 0; n < 4; n++)
            bfr[n] = *(const bf16x8*)&Bs[(size_t)(wc + n * 16 + rsel) * 32 + ksel];
        #pragma unroll
        for (int m = 0; m < 4; m++)
            #pragma unroll
            for (int n = 0; n < 4; n++)
                acc[m][n] = __builtin_amdgcn_mfma_f32_16x16x32_bf16(af[m], bfr[n], acc[m][n], 0, 0, 0);

        asm volatile("" ::: "memory");
        __builtin_amdgcn_s_barrier();    // all waves done reading buf[cur]
        if (ks + 2 < 8) {                // re-stage buf[cur] with tile ks+2
            size_t ko = (size_t)(ks + 2) * 64;
            g2l16(Ab + ko,  (char*)Asb[cur] + (size_t)t * 16);
            g2l16(Bb0 + ko, (char*)Bsb[cur] + (size_t)t * 16);
            g2l16(Bb1 + ko, (char*)Bsb[cur] + (size_t)(512 + t) * 16);
        }
    }

    // epilogue: C/D frag mapping col=lane&15, row=(lane>>4)*4+reg
    int cr = lane >> 4;
    #pragma unroll
    for (int n = 0; n < 4; n++) {
        int colg = wc + n * 16 + rsel;
        float s = scale[colg], sh = shift[colg];
        #pragma unroll
        for (int m = 0; m < 4; m++) {
            int rowb = m0 + wr + m * 16 + cr * 4;
            #pragma unroll
            for (int r = 0; r < 4; r++) {
                int row = rowb + r;
                if (row < M) {
                    float v = fmaxf(acc[m][n][r] * s + sh, 0.f);
                    C[(size_t)row * 256 + colg] = f2b(v);
                }
            }
        }
    }
}

// ---------------- pooling (bf16 in, f32 out, concatenated [g][512]) ----------------
__global__ void pool_seg(const unsigned short* __restrict__ h1,
                         const unsigned short* __restrict__ h2,
                         const int* __restrict__ gstart,
                         float* __restrict__ pcat) {
    int g = blockIdx.x;
    int t = threadIdx.x;
    int s = gstart[g], e = gstart[g + 1];
    float a1 = 0.f, a2 = 0.f;
    for (int n = s; n < e; n++) {
        a1 += b2f(h1[(size_t)n * DIM + t]);
        a2 += b2f(h2[(size_t)n * DIM + t]);
    }
    pcat[(size_t)g * 512 + t]       = a1;
    pcat[(size_t)g * 512 + 256 + t] = a2;
}

// ---------------- head stage 1 (split-K): Hpart[z][500][768] = pcat[:, z*128:(z+1)*128] @ W1-slice ----
__global__ void head1(const float* __restrict__ A,    // [500][512]
                      const float* __restrict__ W1,   // [512][768]
                      float* __restrict__ Hpart) {    // [KSPLIT][500][768]
    __shared__ float As[16][65];
    __shared__ float Bs[16][65];
    int t = threadIdx.x;
    int m0 = blockIdx.y * 64;
    int n0 = blockIdx.x * 64;
    int kz = blockIdx.z * (512 / KSPLIT);
    int tx = t & 15, ty = t >> 4;
    float acc[4][4] = {};
    for (int k0 = kz; k0 < kz + 512 / KSPLIT; k0 += 16) {
        #pragma unroll
        for (int i = 0; i < 4; i++) {
            int r = (t >> 4) + i * 16;
            int k = t & 15;
            int gr = m0 + r;
            As[k][r] = (gr < N_GRAPHS) ? A[(size_t)gr * 512 + k0 + k] : 0.f;
        }
        #pragma unroll
        for (int i = 0; i < 4; i++) {
            int k = (t >> 6) + i * 4;
            int n = t & 63;
            Bs[k][n] = W1[(size_t)(k0 + k) * 768 + n0 + n];
        }
        __syncthreads();
        #pragma unroll
        for (int k = 0; k < 16; k++) {
            float a[4], b[4];
            #pragma unroll
            for (int i = 0; i < 4; i++) a[i] = As[k][ty * 4 + i];
            #pragma unroll
            for (int j = 0; j < 4; j++) b[j] = Bs[k][tx * 4 + j];
            #pragma unroll
            for (int i = 0; i < 4; i++)
                #pragma unroll
                for (int j = 0; j < 4; j++)
                    acc[i][j] += a[i] * b[j];
        }
        __syncthreads();
    }
    float* Hz = Hpart + (size_t)blockIdx.z * N_GRAPHS * 768;
    #pragma unroll
    for (int i = 0; i < 4; i++) {
        int gm = m0 + ty * 4 + i;
        if (gm >= N_GRAPHS) continue;
        #pragma unroll
        for (int j = 0; j < 4; j++) {
            int gn = n0 + tx * 4 + j;
            Hz[(size_t)gm * 768 + gn] = acc[i][j];
        }
    }
}

// ---------------- head stage 2: sum partials + bias + relu, GEMV, log_softmax ----------------
__global__ void head2(const float* __restrict__ Hpart, const float* __restrict__ b1,
                      const float* __restrict__ W2, const float* __restrict__ b2,
                      float* __restrict__ out) {
    int g = blockIdx.x;
    int lane = threadIdx.x;   // 64
    float part[N_OUT];
    #pragma unroll
    for (int o = 0; o < N_OUT; o++) part[o] = 0.f;
    for (int k = lane; k < 768; k += 64) {
        float hv = b1[k];
        #pragma unroll
        for (int z = 0; z < KSPLIT; z++)
            hv += Hpart[((size_t)z * N_GRAPHS + g) * 768 + k];
        hv = fmaxf(hv, 0.f);
        #pragma unroll
        for (int o = 0; o < N_OUT; o++) part[o] += hv * W2[(size_t)k * N_OUT + o];
    }
    #pragma unroll
    for (int o = 0; o < N_OUT; o++) {
        #pragma unroll
        for (int off = 32; off > 0; off >>= 1)
            part[o] += __shfl_down(part[o], off, 64);
    }
    if (lane == 0) {
        float logits[N_OUT];
        float mx = -1e30f;
        #pragma unroll
        for (int o = 0; o < N_OUT; o++) { logits[o] = part[o] + b2[o]; mx = fmaxf(mx, logits[o]); }
        float ssum = 0.f;
        #pragma unroll
        for (int o = 0; o < N_OUT; o++) ssum += expf(logits[o] - mx);
        float lse = logf(ssum);
        #pragma unroll
        for (int o = 0; o < N_OUT; o++)
            out[(size_t)g * N_OUT + o] = logits[o] - mx - lse;
    }
}

extern "C" void kernel_launch(void* const* d_in, const int* in_sizes, int n_in,
                              void* d_out, int out_size, void* d_ws, size_t ws_size,
                              hipStream_t stream) {
    const float* x     = (const float*)d_in[0];
    const int*   ei    = (const int*)d_in[1];
    const int*   batch = (const int*)d_in[2];
    const float* W1a = (const float*)d_in[3];
    const float* b1a = (const float*)d_in[4];
    const float* g1a = (const float*)d_in[5];
    const float* be1a= (const float*)d_in[6];
    const float* m1a = (const float*)d_in[7];
    const float* v1a = (const float*)d_in[8];
    const float* W2a = (const float*)d_in[9];
    const float* b2a = (const float*)d_in[10];
    const float* W1b = (const float*)d_in[11];
    const float* b1b = (const float*)d_in[12];
    const float* g1b = (const float*)d_in[13];
    const float* be1b= (const float*)d_in[14];
    const float* m1b = (const float*)d_in[15];
    const float* v1b = (const float*)d_in[16];
    const float* W2b = (const float*)d_in[17];
    const float* b2b = (const float*)d_in[18];
    const float* lin1_W = (const float*)d_in[19];
    const float* lin1_b = (const float*)d_in[20];
    const float* lin2_W = (const float*)d_in[21];
    const float* lin2_b = (const float*)d_in[22];

    const size_t NBUF = (size_t)MPAD * DIM;
    char* ws = (char*)d_ws;
    unsigned short* agg  = (unsigned short*)ws;            ws += NBUF * 2;
    unsigned short* mid  = (unsigned short*)ws;            ws += NBUF * 2;
    unsigned short* h1   = (unsigned short*)ws;            ws += NBUF * 2;
    unsigned short* h2   = (unsigned short*)ws;            ws += NBUF * 2;
    unsigned short* x_bf = (unsigned short*)ws;            ws += (size_t)N_NODES * DIM * 2;
    unsigned short* Wt   = (unsigned short*)ws;            ws += 4 * 65536 * 2;
    float* ss    = (float*)ws;                             ws += 8 * 256 * 4;
    float* pcat  = (float*)ws;                             ws += (size_t)N_GRAPHS * 512 * 4;
    float* Hpart = (float*)ws;                             ws += (size_t)KSPLIT * N_GRAPHS * 768 * 4;
    int* deg     = (int*)ws;                               ws += (size_t)N_NODES * 4;
    int* cursor  = (int*)ws;                               ws += (size_t)N_NODES * 4;
    int* rowptr  = (int*)ws;                               ws += (size_t)(N_NODES + 1) * 4;
    int* bsum    = (int*)ws;                               ws += 64 * 4;
    int* col     = (int*)ws;                               ws += (size_t)N_EDGES * 4;
    int* gstart  = (int*)ws;

    const int* srcE = ei;
    const int* dstE = ei + N_EDGES;

    const int nscan = (N_NODES + SCAN_BS - 1) / SCAN_BS;

    // ---- CSR build (by dst), shared by both layers ----
    zero_i<<<(N_NODES + 255) / 256, 256, 0, stream>>>(deg, N_NODES);
    hist_dst<<<(N_EDGES + 255) / 256, 256, 0, stream>>>(dstE, deg);
    scan_phase1<<<nscan, SCAN_BS, 0, stream>>>(deg, rowptr, bsum, N_NODES);
    scan_phase2<<<1, 64, 0, stream>>>(bsum, nscan);
    scan_phase3<<<nscan, SCAN_BS, 0, stream>>>(rowptr, cursor, bsum, N_NODES);
    fill_csr<<<(N_EDGES + 255) / 256, 256, 0, stream>>>(srcE, dstE, cursor, col);
    graph_starts<<<2, 256, 0, stream>>>(batch, gstart);

    // ---- precompute ----
    conv_x<<<(N_NODES * DIM / 4 + 255) / 256, 256, 0, stream>>>(
        (const float4*)x, (ushort4*)x_bf, N_NODES * DIM / 4);
    dim3 wt_grid(256, 4);
    conv_wt4<<<wt_grid, 256, 0, stream>>>(W1a, W2a, W1b, W2b, Wt);
    make_ss<<<1, 256, 0, stream>>>(b1a, g1a, be1a, m1a, v1a, ss + 0 * 512, ss + 0 * 512 + 256, 1);
    make_ss<<<1, 256, 0, stream>>>(b2a, nullptr, nullptr, nullptr, nullptr, ss + 1 * 512, ss + 1 * 512 + 256, 0);
    make_ss<<<1, 256, 0, stream>>>(b1b, g1b, be1b, m1b, v1b, ss + 2 * 512, ss + 2 * 512 + 256, 1);
    make_ss<<<1, 256, 0, stream>>>(b2b, nullptr, nullptr, nullptr, nullptr, ss + 3 * 512, ss + 3 * 512 + 256, 0);

    // ---- layer 1 ----
    gather_bf<<<(N_NODES + 3) / 4, 256, 0, stream>>>(x_bf, col, rowptr, agg);
    gemm_bf16<<<MPAD / 128, 512, 0, stream>>>(agg, Wt + 0 * 65536, ss + 0 * 512, ss + 0 * 512 + 256, mid, N_NODES);
    gemm_bf16<<<MPAD / 128, 512, 0, stream>>>(mid, Wt + 1 * 65536, ss + 1 * 512, ss + 1 * 512 + 256, h1, N_NODES);

    // ---- layer 2 ----
    gather_bf<<<(N_NODES + 3) / 4, 256, 0, stream>>>(h1, col, rowptr, agg);
    gemm_bf16<<<MPAD / 128, 512, 0, stream>>>(agg, Wt + 2 * 65536, ss + 2 * 512, ss + 2 * 512 + 256, mid, N_NODES);
    gemm_bf16<<<MPAD / 128, 512, 0, stream>>>(mid, Wt + 3 * 65536, ss + 3 * 512, ss + 3 * 512 + 256, h2, N_NODES);

    // ---- pooling + head ----
    pool_seg<<<N_GRAPHS, 256, 0, stream>>>(h1, h2, gstart, pcat);
    dim3 h1grid(12, 8, KSPLIT);
    head1<<<h1grid, 256, 0, stream>>>(pcat, lin1_W, Hpart);
    head2<<<N_GRAPHS, 64, 0, stream>>>(Hpart, lin1_b, lin2_W, lin2_b, (float*)d_out);
}

// Round 9
// 365.403 us; speedup vs baseline: 1.1300x; 1.0818x over previous
//
#include <hip/hip_runtime.h>

#define N_NODES 50000
#define MPAD 50176            // 784*64, node-buffer row padding for GEMM staging
#define N_EDGES 800000
#define DIM 256
#define N_GRAPHS 500
#define N_OUT 10
#define BN_EPS 1e-5f
#define SCAN_BS 1024
#define KSPLIT 4

typedef unsigned int u32;
typedef short bf16x8 __attribute__((ext_vector_type(8)));
typedef unsigned short us8 __attribute__((ext_vector_type(8)));
typedef float f32x4 __attribute__((ext_vector_type(4)));

typedef __attribute__((address_space(1))) const unsigned int gas_u32;
typedef __attribute__((address_space(3))) unsigned int las_u32;

__device__ inline void g2l16(const void* g, void* l) {
    // async global->LDS, 16 bytes per lane; LDS dest = wave-uniform base + lane*16
    __builtin_amdgcn_global_load_lds((gas_u32*)g, (las_u32*)l, 16, 0, 0);
}

__device__ inline float b2f(unsigned short u) {
    union { u32 i; float f; } c; c.i = ((u32)u) << 16; return c.f;
}
__device__ inline unsigned short f2b(float f) {   // round-to-nearest-even
    u32 x = __builtin_bit_cast(u32, f);
    return (unsigned short)((x + 0x7FFFu + ((x >> 16) & 1u)) >> 16);
}

// swizzled byte address into the 64x256-bf16 mid LDS tile (row stride 512B = 32 slots):
// slot ^= row&31 is bijective per row and de-conflicts stride-512B column reads.
__device__ inline int mid_addr(int row, int col) {
    return row * 512 + ((((col >> 3) ^ (row & 31)) << 4) | ((col & 7) << 1));
}

// ---------------- CSR build ----------------
__global__ void zero_i(int* __restrict__ p, int n) {
    int i = blockIdx.x * blockDim.x + threadIdx.x;
    if (i < n) p[i] = 0;
}
__global__ void hist_dst(const int* __restrict__ dst, int* __restrict__ deg) {
    int e = blockIdx.x * blockDim.x + threadIdx.x;
    if (e < N_EDGES) atomicAdd(&deg[dst[e]], 1);
}
__global__ void scan_phase1(const int* __restrict__ deg, int* __restrict__ rowptr,
                            int* __restrict__ bsum, int n) {
    __shared__ int sh[SCAN_BS];
    int i = blockIdx.x * SCAN_BS + threadIdx.x;
    int v = (i < n) ? deg[i] : 0;
    sh[threadIdx.x] = v;
    __syncthreads();
    for (int off = 1; off < SCAN_BS; off <<= 1) {
        int t = (threadIdx.x >= off) ? sh[threadIdx.x - off] : 0;
        __syncthreads();
        sh[threadIdx.x] += t;
        __syncthreads();
    }
    if (i < n) rowptr[i] = sh[threadIdx.x] - v;
    if (threadIdx.x == SCAN_BS - 1) bsum[blockIdx.x] = sh[threadIdx.x];
}
__global__ void scan_phase2(int* __restrict__ bsum, int nb) {
    if (threadIdx.x == 0 && blockIdx.x == 0) {
        int run = 0;
        for (int b = 0; b < nb; b++) { int v = bsum[b]; bsum[b] = run; run += v; }
    }
}
__global__ void scan_phase3(int* __restrict__ rowptr, int* __restrict__ cursor,
                            const int* __restrict__ bsum, int n) {
    int i = blockIdx.x * SCAN_BS + threadIdx.x;
    if (i < n) {
        int v = rowptr[i] + bsum[blockIdx.x];
        rowptr[i] = v;
        cursor[i] = v;
    }
    if (i == 0) rowptr[n] = N_EDGES;
}
__global__ void fill_csr(const int* __restrict__ src, const int* __restrict__ dst,
                         int* __restrict__ cursor, int* __restrict__ col) {
    int e = blockIdx.x * blockDim.x + threadIdx.x;
    if (e < N_EDGES) {
        int p = atomicAdd(&cursor[dst[e]], 1);
        col[p] = src[e];
    }
}
__global__ void graph_starts(const int* __restrict__ batch, int* __restrict__ gstart) {
    int g = blockIdx.x * blockDim.x + threadIdx.x;
    if (g > N_GRAPHS) return;
    if (g == N_GRAPHS) { gstart[g] = N_NODES; return; }
    int lo = 0, hi = N_NODES;
    while (lo < hi) { int mid = (lo + hi) >> 1; if (batch[mid] < g) lo = mid + 1; else hi = mid; }
    gstart[g] = lo;
}

// ---------------- conversions ----------------
__global__ void conv_x(const float4* __restrict__ in, ushort4* __restrict__ out, int n4) {
    int i = blockIdx.x * blockDim.x + threadIdx.x;
    if (i < n4) {
        float4 v = in[i];
        ushort4 o; o.x = f2b(v.x); o.y = f2b(v.y); o.z = f2b(v.z); o.w = f2b(v.w);
        out[i] = o;
    }
}
// Wt[mat][n][k] = bf16(W[mat][k][n])
__global__ void conv_wt4(const float* __restrict__ W0, const float* __restrict__ W1,
                         const float* __restrict__ W2, const float* __restrict__ W3,
                         unsigned short* __restrict__ Wt) {
    int mat = blockIdx.y;
    const float* W = (mat == 0) ? W0 : (mat == 1) ? W1 : (mat == 2) ? W2 : W3;
    int n = blockIdx.x;
    int k = threadIdx.x;
    Wt[((size_t)mat << 16) + (size_t)n * 256 + k] = f2b(W[(size_t)k * 256 + n]);
}
__global__ void make_ss(const float* __restrict__ bias, const float* __restrict__ gamma,
                        const float* __restrict__ beta, const float* __restrict__ mean,
                        const float* __restrict__ var, float* __restrict__ scale,
                        float* __restrict__ shift) {
    int i = threadIdx.x;
    float s = gamma[i] * rsqrtf(var[i] + BN_EPS);
    scale[i] = s;
    shift[i] = (bias[i] - mean[i]) * s + beta[i];
}

// ---------------- gather aggregate (bf16): out[i] = feat[i] + sum_{j in N(i)} feat[j] ----------------
// one wave per node; two 32-lane halves own alternate edges; 16 B/lane loads; x4 unroll (8 streams/wave).
__global__ void gather_bf(const unsigned short* __restrict__ feat,
                          const int* __restrict__ col,
                          const int* __restrict__ rowptr,
                          unsigned short* __restrict__ out) {
    int node = blockIdx.x * 4 + (threadIdx.x >> 6);
    if (node >= N_NODES) return;
    int lane = threadIdx.x & 63;
    int half = lane >> 5;
    int d8 = (lane & 31) * 8;          // 8 bf16 = 16 B per lane
    float acc[8];
    #pragma unroll
    for (int j = 0; j < 8; j++) acc[j] = 0.f;
    if (half == 0) {
        us8 own = *reinterpret_cast<const us8*>(&feat[(size_t)node * DIM + d8]);
        #pragma unroll
        for (int j = 0; j < 8; j++) acc[j] = b2f((unsigned short)own[j]);
    }
    int s = rowptr[node], e = rowptr[node + 1];
    int i = s + half;
    for (; i + 6 < e; i += 8) {        // 4 edges per half per iter
        int n0 = col[i], n1 = col[i + 2], n2 = col[i + 4], n3 = col[i + 6];
        us8 v0 = *reinterpret_cast<const us8*>(&feat[(size_t)n0 * DIM + d8]);
        us8 v1 = *reinterpret_cast<const us8*>(&feat[(size_t)n1 * DIM + d8]);
        us8 v2 = *reinterpret_cast<const us8*>(&feat[(size_t)n2 * DIM + d8]);
        us8 v3 = *reinterpret_cast<const us8*>(&feat[(size_t)n3 * DIM + d8]);
        #pragma unroll
        for (int j = 0; j < 8; j++)
            acc[j] += (b2f((unsigned short)v0[j]) + b2f((unsigned short)v1[j]))
                    + (b2f((unsigned short)v2[j]) + b2f((unsigned short)v3[j]));
    }
    for (; i < e; i += 2) {
        int n0 = col[i];
        us8 v0 = *reinterpret_cast<const us8*>(&feat[(size_t)n0 * DIM + d8]);
        #pragma unroll
        for (int j = 0; j < 8; j++) acc[j] += b2f((unsigned short)v0[j]);
    }
    #pragma unroll
    for (int j = 0; j < 8; j++) acc[j] += __shfl_xor(acc[j], 32, 64);
    if (half == 0) {
        us8 o;
        #pragma unroll
        for (int j = 0; j < 8; j++) o[j] = (short)f2b(acc[j]);
        *reinterpret_cast<us8*>(&out[(size_t)node * DIM + d8]) = o;
    }
}

// ---------------- fused GIN MLP:  H = relu(relu(bn(A@W1)) @ W2 + b2), all in one block pass ------
// 256 threads, 64-row tile, 4 waves as 1M x 4N (wave 64x64), BK=32, K=256.
// Phase 1: A@W1 -> mid (LDS, swizzled).  Phase 2: mid@W2 -> H.  W2 tiles prefetched during phase 1.
__global__ __launch_bounds__(256, 2)
void fused_mlp(const unsigned short* __restrict__ A,
               const unsigned short* __restrict__ W1t,   // [256][256], W1t[n][k]
               const unsigned short* __restrict__ W2t,   // [256][256], W2t[n][k]
               const float* __restrict__ scale1,
               const float* __restrict__ shift1,
               const float* __restrict__ shift2,         // b2
               unsigned short* __restrict__ H, int M) {
    __shared__ __align__(16) unsigned short Asb[2][64 * 32];    // 2 x 4 KB
    __shared__ __align__(16) unsigned short Bsb[2][256 * 32];   // 2 x 16 KB
    __shared__ __align__(16) unsigned short midb[64 * 256];     // 32 KB, swizzled

    int t = threadIdx.x;
    int wave = t >> 6, lane = t & 63;
    int m0 = blockIdx.x * 64;
    int wc = wave * 64;
    int rsel = lane & 15;
    int ksel = (lane >> 4) * 8;
    int cr = lane >> 4;

    // preload epilogue constants FIRST so no vector loads interleave with counted vmcnt
    float s1[4], sh1[4], sh2[4];
    #pragma unroll
    for (int n = 0; n < 4; n++) {
        int colg = wc + n * 16 + rsel;
        s1[n]  = scale1[colg];
        sh1[n] = shift1[colg];
        sh2[n] = shift2[colg];
    }

    int cb = (t & 3) * 16;
    const char* Ab  = (const char*)A   + (size_t)(m0 + (t >> 2)) * 512 + cb;
    const char* B1b = (const char*)W1t + (size_t)(t >> 2) * 512 + cb;
    const char* B2b = (const char*)W2t + (size_t)(t >> 2) * 512 + cb;

    f32x4 acc[4][4];
    #pragma unroll
    for (int m = 0; m < 4; m++)
        #pragma unroll
        for (int n = 0; n < 4; n++)
            acc[m][n] = (f32x4){0.f, 0.f, 0.f, 0.f};

    // prologue: stage phase-1 tiles 0,1 (A: 1 issue, W1: 4 issues per thread per tile)
    #pragma unroll
    for (int p = 0; p < 2; p++) {
        size_t ko = (size_t)p * 64;
        g2l16(Ab + ko, (char*)Asb[p] + (size_t)t * 16);
        #pragma unroll
        for (int i = 0; i < 4; i++)
            g2l16(B1b + (size_t)i * 32768 + ko, (char*)Bsb[p] + (size_t)(i * 256 + t) * 16);
    }

    // ---- phase 1: acc = A @ W1 ----
    #pragma unroll
    for (int ks = 0; ks < 8; ks++) {
        const int cur = ks & 1;
        if (ks < 7) asm volatile("s_waitcnt vmcnt(5)" ::: "memory");   // tile ks done, ks+1 (and W2t0 at ks=7) in flight
        else        asm volatile("s_waitcnt vmcnt(4)" ::: "memory");
        __builtin_amdgcn_s_barrier();
        asm volatile("" ::: "memory");

        const unsigned short* As = Asb[cur];
        const unsigned short* Bs = Bsb[cur];
        bf16x8 af[4], bfr[4];
        #pragma unroll
        for (int m = 0; m < 4; m++)
            af[m] = *(const bf16x8*)&As[(size_t)(m * 16 + rsel) * 32 + ksel];
        #pragma unroll
        for (int n = 0; n < 4; n++)
            bfr[n] = *(const bf16x8*)&Bs[(size_t)(wc + n * 16 + rsel) * 32 + ksel];
        #pragma unroll
        for (int m = 0; m < 4; m++)
            #pragma unroll
            for (int n = 0; n < 4; n++)
                acc[m][n] = __builtin_amdgcn_mfma_f32_16x16x32_bf16(af[m], bfr[n], acc[m][n], 0, 0, 0);

        asm volatile("" ::: "memory");
        __builtin_amdgcn_s_barrier();
        if (ks + 2 < 8) {            // restage buf[cur] with phase-1 tile ks+2
            size_t ko = (size_t)(ks + 2) * 64;
            g2l16(Ab + ko, (char*)Asb[cur] + (size_t)t * 16);
            #pragma unroll
            for (int i = 0; i < 4; i++)
                g2l16(B1b + (size_t)i * 32768 + ko, (char*)Bsb[cur] + (size_t)(i * 256 + t) * 16);
        } else if (ks == 6) {        // Bsb[0] free -> prefetch W2 tile 0
            #pragma unroll
            for (int i = 0; i < 4; i++)
                g2l16(B2b + (size_t)i * 32768, (char*)Bsb[0] + (size_t)(i * 256 + t) * 16);
        } else {                     // ks == 7: Bsb[1] free -> prefetch W2 tile 1
            #pragma unroll
            for (int i = 0; i < 4; i++)
                g2l16(B2b + (size_t)i * 32768 + 64, (char*)Bsb[1] + (size_t)(i * 256 + t) * 16);
        }
    }

    // ---- epilogue 1: mid = relu(acc*scale1 + shift1) -> bf16 -> swizzled LDS; reset acc ----
    #pragma unroll
    for (int n = 0; n < 4; n++) {
        int colg = wc + n * 16 + rsel;
        #pragma unroll
        for (int m = 0; m < 4; m++) {
            int rowb = m * 16 + cr * 4;
            #pragma unroll
            for (int r = 0; r < 4; r++) {
                float v = fmaxf(acc[m][n][r] * s1[n] + sh1[n], 0.f);
                *(unsigned short*)((char*)midb + mid_addr(rowb + r, colg)) = f2b(v);
                acc[m][n][r] = 0.f;
            }
        }
    }
    asm volatile("s_waitcnt lgkmcnt(0)" ::: "memory");
    __builtin_amdgcn_s_barrier();
    asm volatile("" ::: "memory");

    // ---- phase 2: acc = mid @ W2 ----
    #pragma unroll
    for (int ks = 0; ks < 8; ks++) {
        const int cur = ks & 1;
        if (ks < 7) asm volatile("s_waitcnt vmcnt(4)" ::: "memory");   // W2 tile ks done, ks+1 in flight
        else        asm volatile("s_waitcnt vmcnt(0)" ::: "memory");
        __builtin_amdgcn_s_barrier();
        asm volatile("" ::: "memory");

        const unsigned short* Bs = Bsb[cur];
        bf16x8 af[4], bfr[4];
        #pragma unroll
        for (int m = 0; m < 4; m++)
            af[m] = *(const bf16x8*)((const char*)midb + mid_addr(m * 16 + rsel, ks * 32 + ksel));
        #pragma unroll
        for (int n = 0; n < 4; n++)
            bfr[n] = *(const bf16x8*)&Bs[(size_t)(wc + n * 16 + rsel) * 32 + ksel];
        #pragma unroll
        for (int m = 0; m < 4; m++)
            #pragma unroll
            for (int n = 0; n < 4; n++)
                acc[m][n] = __builtin_amdgcn_mfma_f32_16x16x32_bf16(af[m], bfr[n], acc[m][n], 0, 0, 0);

        asm volatile("" ::: "memory");
        __builtin_amdgcn_s_barrier();
        if (ks + 2 < 8) {            // restage buf[cur] with W2 tile ks+2
            size_t ko = (size_t)(ks + 2) * 64;
            #pragma unroll
            for (int i = 0; i < 4; i++)
                g2l16(B2b + (size_t)i * 32768 + ko, (char*)Bsb[cur] + (size_t)(i * 256 + t) * 16);
        }
    }

    // ---- epilogue 2: H = relu(acc + b2) ----
    #pragma unroll
    for (int n = 0; n < 4; n++) {
        int colg = wc + n * 16 + rsel;
        #pragma unroll
        for (int m = 0; m < 4; m++) {
            int rowb = m0 + m * 16 + cr * 4;
            #pragma unroll
            for (int r = 0; r < 4; r++) {
                int row = rowb + r;
                if (row < M) {
                    float v = fmaxf(acc[m][n][r] + sh2[n], 0.f);
                    H[(size_t)row * 256 + colg] = f2b(v);
                }
            }
        }
    }
}

// ---------------- pooling (bf16 in, f32 out, concatenated [g][512]) ----------------
__global__ void pool_seg(const unsigned short* __restrict__ h1,
                         const unsigned short* __restrict__ h2,
                         const int* __restrict__ gstart,
                         float* __restrict__ pcat) {
    int g = blockIdx.x;
    int t = threadIdx.x;
    int s = gstart[g], e = gstart[g + 1];
    float a1 = 0.f, a2 = 0.f;
    for (int n = s; n < e; n++) {
        a1 += b2f(h1[(size_t)n * DIM + t]);
        a2 += b2f(h2[(size_t)n * DIM + t]);
    }
    pcat[(size_t)g * 512 + t]       = a1;
    pcat[(size_t)g * 512 + 256 + t] = a2;
}

// ---------------- head stage 1 (split-K): Hpart[z][500][768] = pcat[:, z*128:(z+1)*128] @ W1-slice ----
__global__ void head1(const float* __restrict__ A,    // [500][512]
                      const float* __restrict__ W1,   // [512][768]
                      float* __restrict__ Hpart) {    // [KSPLIT][500][768]
    __shared__ float As[16][65];
    __shared__ float Bs[16][65];
    int t = threadIdx.x;
    int m0 = blockIdx.y * 64;
    int n0 = blockIdx.x * 64;
    int kz = blockIdx.z * (512 / KSPLIT);
    int tx = t & 15, ty = t >> 4;
    float acc[4][4] = {};
    for (int k0 = kz; k0 < kz + 512 / KSPLIT; k0 += 16) {
        #pragma unroll
        for (int i = 0; i < 4; i++) {
            int r = (t >> 4) + i * 16;
            int k = t & 15;
            int gr = m0 + r;
            As[k][r] = (gr < N_GRAPHS) ? A[(size_t)gr * 512 + k0 + k] : 0.f;
        }
        #pragma unroll
        for (int i = 0; i < 4; i++) {
            int k = (t >> 6) + i * 4;
            int n = t & 63;
            Bs[k][n] = W1[(size_t)(k0 + k) * 768 + n0 + n];
        }
        __syncthreads();
        #pragma unroll
        for (int k = 0; k < 16; k++) {
            float a[4], b[4];
            #pragma unroll
            for (int i = 0; i < 4; i++) a[i] = As[k][ty * 4 + i];
            #pragma unroll
            for (int j = 0; j < 4; j++) b[j] = Bs[k][tx * 4 + j];
            #pragma unroll
            for (int i = 0; i < 4; i++)
                #pragma unroll
                for (int j = 0; j < 4; j++)
                    acc[i][j] += a[i] * b[j];
        }
        __syncthreads();
    }
    float* Hz = Hpart + (size_t)blockIdx.z * N_GRAPHS * 768;
    #pragma unroll
    for (int i = 0; i < 4; i++) {
        int gm = m0 + ty * 4 + i;
        if (gm >= N_GRAPHS) continue;
        #pragma unroll
        for (int j = 0; j < 4; j++) {
            int gn = n0 + tx * 4 + j;
            Hz[(size_t)gm * 768 + gn] = acc[i][j];
        }
    }
}

// ---------------- head stage 2: sum partials + bias + relu, GEMV, log_softmax ----------------
__global__ void head2(const float* __restrict__ Hpart, const float* __restrict__ b1,
                      const float* __restrict__ W2, const float* __restrict__ b2,
                      float* __restrict__ out) {
    int g = blockIdx.x;
    int lane = threadIdx.x;   // 64
    float part[N_OUT];
    #pragma unroll
    for (int o = 0; o < N_OUT; o++) part[o] = 0.f;
    for (int k = lane; k < 768; k += 64) {
        float hv = b1[k];
        #pragma unroll
        for (int z = 0; z < KSPLIT; z++)
            hv += Hpart[((size_t)z * N_GRAPHS + g) * 768 + k];
        hv = fmaxf(hv, 0.f);
        #pragma unroll
        for (int o = 0; o < N_OUT; o++) part[o] += hv * W2[(size_t)k * N_OUT + o];
    }
    #pragma unroll
    for (int o = 0; o < N_OUT; o++) {
        #pragma unroll
        for (int off = 32; off > 0; off >>= 1)
            part[o] += __shfl_down(part[o], off, 64);
    }
    if (lane == 0) {
        float logits[N_OUT];
        float mx = -1e30f;
        #pragma unroll
        for (int o = 0; o < N_OUT; o++) { logits[o] = part[o] + b2[o]; mx = fmaxf(mx, logits[o]); }
        float ssum = 0.f;
        #pragma unroll
        for (int o = 0; o < N_OUT; o++) ssum += expf(logits[o] - mx);
        float lse = logf(ssum);
        #pragma unroll
        for (int o = 0; o < N_OUT; o++)
            out[(size_t)g * N_OUT + o] = logits[o] - mx - lse;
    }
}

extern "C" void kernel_launch(void* const* d_in, const int* in_sizes, int n_in,
                              void* d_out, int out_size, void* d_ws, size_t ws_size,
                              hipStream_t stream) {
    const float* x     = (const float*)d_in[0];
    const int*   ei    = (const int*)d_in[1];
    const int*   batch = (const int*)d_in[2];
    const float* W1a = (const float*)d_in[3];
    const float* b1a = (const float*)d_in[4];
    const float* g1a = (const float*)d_in[5];
    const float* be1a= (const float*)d_in[6];
    const float* m1a = (const float*)d_in[7];
    const float* v1a = (const float*)d_in[8];
    const float* W2a = (const float*)d_in[9];
    const float* b2a = (const float*)d_in[10];
    const float* W1b = (const float*)d_in[11];
    const float* b1b = (const float*)d_in[12];
    const float* g1b = (const float*)d_in[13];
    const float* be1b= (const float*)d_in[14];
    const float* m1b = (const float*)d_in[15];
    const float* v1b = (const float*)d_in[16];
    const float* W2b = (const float*)d_in[17];
    const float* b2b = (const float*)d_in[18];
    const float* lin1_W = (const float*)d_in[19];
    const float* lin1_b = (const float*)d_in[20];
    const float* lin2_W = (const float*)d_in[21];
    const float* lin2_b = (const float*)d_in[22];

    const size_t NBUF = (size_t)MPAD * DIM;
    char* ws = (char*)d_ws;
    unsigned short* agg  = (unsigned short*)ws;            ws += NBUF * 2;
    unsigned short* h1   = (unsigned short*)ws;            ws += NBUF * 2;
    unsigned short* h2   = (unsigned short*)ws;            ws += NBUF * 2;
    unsigned short* x_bf = (unsigned short*)ws;            ws += (size_t)N_NODES * DIM * 2;
    unsigned short* Wt   = (unsigned short*)ws;            ws += 4 * 65536 * 2;
    float* ss    = (float*)ws;                             ws += 4 * 256 * 4;   // 2x(scale,shift)
    float* pcat  = (float*)ws;                             ws += (size_t)N_GRAPHS * 512 * 4;
    float* Hpart = (float*)ws;                             ws += (size_t)KSPLIT * N_GRAPHS * 768 * 4;
    int* deg     = (int*)ws;                               ws += (size_t)N_NODES * 4;
    int* cursor  = (int*)ws;                               ws += (size_t)N_NODES * 4;
    int* rowptr  = (int*)ws;                               ws += (size_t)(N_NODES + 1) * 4;
    int* bsum    = (int*)ws;                               ws += 64 * 4;
    int* col     = (int*)ws;                               ws += (size_t)N_EDGES * 4;
    int* gstart  = (int*)ws;

    const int* srcE = ei;
    const int* dstE = ei + N_EDGES;

    const int nscan = (N_NODES + SCAN_BS - 1) / SCAN_BS;

    // ---- CSR build (by dst), shared by both layers ----
    zero_i<<<(N_NODES + 255) / 256, 256, 0, stream>>>(deg, N_NODES);
    hist_dst<<<(N_EDGES + 255) / 256, 256, 0, stream>>>(dstE, deg);
    scan_phase1<<<nscan, SCAN_BS, 0, stream>>>(deg, rowptr, bsum, N_NODES);
    scan_phase2<<<1, 64, 0, stream>>>(bsum, nscan);
    scan_phase3<<<nscan, SCAN_BS, 0, stream>>>(rowptr, cursor, bsum, N_NODES);
    fill_csr<<<(N_EDGES + 255) / 256, 256, 0, stream>>>(srcE, dstE, cursor, col);
    graph_starts<<<2, 256, 0, stream>>>(batch, gstart);

    // ---- precompute ----
    conv_x<<<(N_NODES * DIM / 4 + 255) / 256, 256, 0, stream>>>(
        (const float4*)x, (ushort4*)x_bf, N_NODES * DIM / 4);
    dim3 wt_grid(256, 4);
    conv_wt4<<<wt_grid, 256, 0, stream>>>(W1a, W2a, W1b, W2b, Wt);
    make_ss<<<1, 256, 0, stream>>>(b1a, g1a, be1a, m1a, v1a, ss + 0 * 512, ss + 0 * 512 + 256);
    make_ss<<<1, 256, 0, stream>>>(b1b, g1b, be1b, m1b, v1b, ss + 1 * 512, ss + 1 * 512 + 256);

    // ---- layer 1 ----
    gather_bf<<<(N_NODES + 3) / 4, 256, 0, stream>>>(x_bf, col, rowptr, agg);
    fused_mlp<<<MPAD / 64, 256, 0, stream>>>(agg, Wt + 0 * 65536, Wt + 1 * 65536,
                                             ss + 0 * 512, ss + 0 * 512 + 256, b2a, h1, N_NODES);

    // ---- layer 2 ----
    gather_bf<<<(N_NODES + 3) / 4, 256, 0, stream>>>(h1, col, rowptr, agg);
    fused_mlp<<<MPAD / 64, 256, 0, stream>>>(agg, Wt + 2 * 65536, Wt + 3 * 65536,
                                             ss + 1 * 512, ss + 1 * 512 + 256, b2b, h2, N_NODES);

    // ---- pooling + head ----
    pool_seg<<<N_GRAPHS, 256, 0, stream>>>(h1, h2, gstart, pcat);
    dim3 h1grid(12, 8, KSPLIT);
    head1<<<h1grid, 256, 0, stream>>>(pcat, lin1_W, Hpart);
    head2<<<N_GRAPHS, 64, 0, stream>>>(Hpart, lin1_b, lin2_W, lin2_b, (float*)d_out);
}